// Round 1
// baseline (3302.834 us; speedup 1.0000x reference)
//
#include <hip/hip_runtime.h>
#include <stdint.h>

// Problem constants (fixed by setup_inputs)
#define PN     512
#define NFREE  50000
#define NCND   100000
#define NNODE  100512
#define NEDGE  300000
#define KK     10
#define NLOOP  5
#define EPSV   1e-5f

#define HSIZE  (1u<<20)
#define HMASK  (HSIZE-1)
#define E0CAP  4096
#define EMPTYK 0xFFFFFFFFFFFFFFFFull

// workspace layout (bytes) — total ~9.9 MB
#define OFF_HASH  ((size_t)0)
#define OFF_CPOS  (OFF_HASH + (size_t)HSIZE*8)
#define OFF_CSQ   (OFF_CPOS + (size_t)2*NCND*4)
#define OFF_SUMC  (OFF_CSQ + (size_t)NCND*4)
#define OFF_SUMC2 (OFF_SUMC + 128)
#define OFF_MEAN  (OFF_SUMC2 + 128)
#define OFF_RSTD  (OFF_MEAN + 128)
#define OFF_WCU   (OFF_RSTD + 128)
#define OFF_WCV   (OFF_WCU + 4096)
#define OFF_BU    (OFF_WCV + 4096)
#define OFF_BV    (OFF_BU + 128)
#define OFF_CPATH (OFF_BV + 128)
#define OFF_CFREE (OFF_CPATH + 128)
#define OFF_CCOL  (OFF_CFREE + 128)
#define OFF_PATH  (OFF_CCOL + 128)
#define OFF_UPATH (OFF_PATH + 4096)
#define OFF_VDST  (OFF_UPATH + 65536)
#define OFF_SBUF  (OFF_VDST + 65536)
#define OFF_E0S   (OFF_SBUF + 65536)
#define OFF_E0D   (OFF_E0S + (size_t)E0CAP*4)
#define OFF_DEG0  (OFF_E0D + (size_t)E0CAP*4)
#define OFF_E0C   (OFF_DEG0 + 2048)
#define OFF_KSRC  (OFF_E0C + 64)
#define OFF_KKEEP (OFF_KSRC + (size_t)PN*KK*4)

#define WS_F(o)  ((float*)(ws + (o)))
#define WS_I(o)  ((int*)(ws + (o)))
#define WS_H(o)  ((unsigned long long*)(ws + (o)))

__device__ __forceinline__ bool lexless(float da, int ia, float db, int ib) {
  return (da < db) || (da == db && ia < ib);
}

__device__ __forceinline__ uint32_t hslot(unsigned long long key) {
  return (uint32_t)((key * 0x9E3779B97F4A7C15ull) >> 40) & HMASK;
}

// ---------------- setup kernels (once per launch) ----------------

__global__ __launch_bounds__(256) void k_init(char* __restrict__ ws,
                                              const float* __restrict__ path_in) {
  unsigned i = blockIdx.x * 256u + threadIdx.x;
  WS_H(OFF_HASH)[i] = EMPTYK;                 // grid sized exactly HSIZE
  if (i < 1024) WS_F(OFF_PATH)[i] = path_in[i];
  if (i < 512)  WS_I(OFF_DEG0)[i] = 0;
  if (i < 32) { WS_F(OFF_SUMC)[i] = 0.f; WS_F(OFF_SUMC2)[i] = 0.f; }
  if (i == 0)   *WS_I(OFF_E0C) = 0;
}

// candidate positions, squared norms, h1 feature sums (BN stats, cand part)
__global__ __launch_bounds__(256) void k_cand(char* __restrict__ ws,
    const float* __restrict__ freep, const float* __restrict__ collp,
    const float* __restrict__ ncw1, const float* __restrict__ ncb1) {
  __shared__ float ls[64];
  int tid = threadIdx.x;
  if (tid < 64) ls[tid] = 0.f;
  __syncthreads();
  int j = blockIdx.x * 256 + tid;
  float c0 = 0.f, c1 = 0.f;
  bool valid = (j < NCND);
  if (valid) {
    if (j < NFREE) { c0 = freep[2*j];          c1 = freep[2*j+1]; }
    else           { c0 = collp[2*(j-NFREE)];  c1 = collp[2*(j-NFREE)+1]; }
    WS_F(OFF_CPOS)[2*j] = c0; WS_F(OFF_CPOS)[2*j+1] = c1;
    WS_F(OFF_CSQ)[j] = c0*c0 + c1*c1;
  }
  for (int ff = 0; ff < 32; ff++) {
    int f = (tid + ff) & 31;                  // stagger → no LDS same-addr pileup
    if (valid) {
      float cls = (j < NFREE) ? (ncw1[96+f] + ncb1[f]) : (ncw1[128+f] + ncb1[f]);
      float h = fmaf(c1, ncw1[32+f], fmaf(c0, ncw1[f], cls));
      atomicAdd(&ls[f], h);
      atomicAdd(&ls[32+f], h*h);
    }
  }
  __syncthreads();
  if (tid < 32) {
    atomicAdd(&WS_F(OFF_SUMC)[tid],  ls[tid]);
    atomicAdd(&WS_F(OFF_SUMC2)[tid], ls[32+tid]);
  }
}

// combined weights: Wcu = ncW2·(W1a+W1b), Wcv = ncW2·(W1c−W1a), biases, class consts
__global__ __launch_bounds__(1024) void k_wprep(char* __restrict__ ws,
    const float* __restrict__ m0w1, const float* __restrict__ m0b1,
    const float* __restrict__ ncw1, const float* __restrict__ ncb1,
    const float* __restrict__ ncw2, const float* __restrict__ ncb2) {
  __shared__ float Wu[1024], Wv[1024];
  int tid = threadIdx.x, k = tid >> 5, g = tid & 31;
  float a = m0w1[k*32+g], b = m0w1[(k+32)*32+g], c = m0w1[(k+64)*32+g];
  Wu[tid] = a + b;  Wv[tid] = c - a;
  __syncthreads();
  float au = 0.f, av = 0.f;
  #pragma unroll
  for (int f = 0; f < 32; f++) {
    float w2 = ncw2[k*32+f];
    au = fmaf(w2, Wu[f*32+g], au);
    av = fmaf(w2, Wv[f*32+g], av);
  }
  WS_F(OFF_WCU)[tid] = au;  WS_F(OFF_WCV)[tid] = av;
  if (tid < 32) {
    float bu = 0.f, bv = 0.f;
    #pragma unroll
    for (int f = 0; f < 32; f++) {
      bu = fmaf(ncb2[f], Wu[f*32+tid], bu);
      bv = fmaf(ncb2[f], Wv[f*32+tid], bv);
    }
    WS_F(OFF_BU)[tid] = bu;
    WS_F(OFF_BV)[tid] = bv + m0b1[tid];       // fold mp0_b1 into dst-side
    WS_F(OFF_CPATH)[tid] = ncw1[64+tid]  + ncb1[tid];
    WS_F(OFF_CFREE)[tid] = ncw1[96+tid]  + ncb1[tid];
    WS_F(OFF_CCOL)[tid]  = ncw1[128+tid] + ncb1[tid];
  }
}

// hash-insert fixed edges (dedupe); compact kept edges with dst<PN; deg0 histogram
__global__ __launch_bounds__(256) void k_edges(char* __restrict__ ws,
                                               const int* __restrict__ ei) {
  int e = blockIdx.x * 256 + threadIdx.x;
  if (e >= NEDGE) return;
  int src = ei[e], dst = ei[NEDGE + e];
  unsigned long long key = (unsigned long long)src * NNODE + (unsigned long long)dst;
  unsigned long long* hash = WS_H(OFF_HASH);
  uint32_t slot = hslot(key);
  bool win = false;
  for (;;) {
    unsigned long long prev = atomicCAS(&hash[slot], EMPTYK, key);
    if (prev == EMPTYK) { win = true; break; }
    if (prev == key)    { break; }            // duplicate pair
    slot = (slot + 1) & HMASK;
  }
  if (win && dst < PN) {
    int pos = atomicAdd(WS_I(OFF_E0C), 1);
    if (pos < E0CAP) {
      WS_I(OFF_E0S)[pos] = src;
      WS_I(OFF_E0D)[pos] = dst;
      atomicAdd(&WS_I(OFF_DEG0)[dst], 1);
    }
  }
}

// ---------------- per-loop kernels ----------------

// blocks 0..511: kNN for path node b.  block 512: BN stats + u/v for path nodes + zero S.
__global__ __launch_bounds__(256) void k_loopA(char* __restrict__ ws,
    const float* __restrict__ ncw1, const float* __restrict__ gamma,
    const float* __restrict__ beta) {
  __shared__ float sd[2560];
  __shared__ int   si[2560];
  int tid = threadIdx.x, b = blockIdx.x;
  float* pathb = WS_F(OFF_PATH);

  if (b < PN) {
    const float2* cp2 = (const float2*)WS_F(OFF_CPOS);
    const float*  csq = WS_F(OFF_CSQ);
    float p0 = pathb[2*b], p1 = pathb[2*b+1];
    float psq = p0*p0 + p1*p1;
    float bd[10]; int bi[10];
    #pragma unroll
    for (int k = 0; k < 10; k++) { bd[k] = 3.4e38f; bi[k] = 0x7FFFFFFF; }
    for (int j = tid; j < NCND; j += 256) {
      float2 c = cp2[j];
      float d2 = (psq + csq[j]) - 2.f * fmaf(p1, c.y, p0 * c.x);
      if (lexless(d2, j, bd[9], bi[9])) {
        bool placed = false;
        #pragma unroll
        for (int k = 9; k > 0; k--) {
          bool shift = !placed && lexless(d2, j, bd[k-1], bi[k-1]);
          bool here  = !placed && !shift;
          if (here)       { bd[k] = d2;     bi[k] = j;       placed = true; }
          else if (shift) { bd[k] = bd[k-1]; bi[k] = bi[k-1]; }
        }
        if (!placed) { bd[0] = d2; bi[0] = j; }
      }
    }
    #pragma unroll
    for (int k = 0; k < 10; k++) { sd[tid*10+k] = bd[k]; si[tid*10+k] = bi[k]; }
    __syncthreads();
    for (int stride = 128; stride > 0; stride >>= 1) {
      if (tid < stride) {
        float rd[10]; int ri[10];
        int ia = 0, ib = 0;
        #pragma unroll
        for (int k = 0; k < 10; k++) {
          float da = sd[tid*10+ia],          db = sd[(tid+stride)*10+ib];
          int   xa = si[tid*10+ia],          xb = si[(tid+stride)*10+ib];
          bool takeA = lexless(da, xa, db, xb);
          if (takeA) { rd[k] = da; ri[k] = xa; ia++; }
          else       { rd[k] = db; ri[k] = xb; ib++; }
        }
        #pragma unroll
        for (int k = 0; k < 10; k++) { sd[tid*10+k] = rd[k]; si[tid*10+k] = ri[k]; }
      }
      __syncthreads();
    }
    if (tid == 0) {
      unsigned long long* hash = WS_H(OFF_HASH);
      for (int k = 0; k < 10; k++) {
        int j = si[k];
        int srcg = j + PN;
        unsigned long long key = (unsigned long long)srcg * NNODE + (unsigned long long)b;
        uint32_t slot = hslot(key);
        int keep = 1;
        for (;;) {
          unsigned long long v = hash[slot];
          if (v == EMPTYK) break;
          if (v == key) { keep = 0; break; }   // duplicate of a fixed edge
          slot = (slot + 1) & HMASK;
        }
        WS_I(OFF_KSRC)[b*KK+k]  = srcg;
        WS_I(OFF_KKEEP)[b*KK+k] = keep;
      }
    }
  } else {
    // ---- BN stats over path rows (cand part precomputed) ----
    if (tid < 64) sd[tid] = 0.f;
    __syncthreads();
    const float* cpath = WS_F(OFF_CPATH);
    for (int r = tid; r < PN; r += 256) {
      float p0 = pathb[2*r], p1 = pathb[2*r+1];
      for (int ff = 0; ff < 32; ff++) {
        int f = (tid + ff) & 31;
        float h = fmaf(p1, ncw1[32+f], fmaf(p0, ncw1[f], cpath[f]));
        atomicAdd(&sd[f], h);
        atomicAdd(&sd[32+f], h*h);
      }
    }
    __syncthreads();
    if (tid < 32) {
      float mean = (WS_F(OFF_SUMC)[tid]  + sd[tid])    * (1.f / NNODE);
      float ex2  = (WS_F(OFF_SUMC2)[tid] + sd[32+tid]) * (1.f / NNODE);
      float var  = ex2 - mean * mean;
      float rs   = 1.0f / sqrtf(var + EPSV);
      WS_F(OFF_MEAN)[tid] = mean; WS_F(OFF_RSTD)[tid] = rs;
      sd[64+tid] = mean; sd[96+tid] = rs;
    }
    __syncthreads();
    // ---- u/v for all 512 path nodes ----
    const float* wcu = WS_F(OFF_WCU); const float* wcv = WS_F(OFF_WCV);
    const float* bu  = WS_F(OFF_BU);  const float* bv  = WS_F(OFF_BV);
    for (int i = tid; i < PN; i += 256) {
      float p0 = pathb[2*i], p1 = pathb[2*i+1];
      float xn[32];
      #pragma unroll
      for (int f = 0; f < 32; f++) {
        float h = fmaf(p1, ncw1[32+f], fmaf(p0, ncw1[f], cpath[f]));
        float t = (h - sd[64+f]) * sd[96+f];
        t = fmaf(t, gamma[f], beta[f]);
        xn[f] = t > 0.f ? t : 0.f;
      }
      for (int f = 0; f < 32; f++) {
        float au = bu[f], av = bv[f];
        #pragma unroll
        for (int k = 0; k < 32; k++) {
          au = fmaf(xn[k], wcu[k*32+f], au);
          av = fmaf(xn[k], wcv[k*32+f], av);
        }
        WS_F(OFF_UPATH)[i*32+f] = au;
        WS_F(OFF_VDST)[i*32+f]  = av;
      }
    }
    for (int i = tid; i < PN*32; i += 256) WS_F(OFF_SBUF)[i] = 0.f;
  }
}

// per-edge: r = relu(u[src]+v[dst]) accumulated into S[dst]
__global__ __launch_bounds__(256) void k_loopB(char* __restrict__ ws,
    const float* __restrict__ ncw1, const float* __restrict__ gamma,
    const float* __restrict__ beta) {
  int t = blockIdx.x * 256 + threadIdx.x;
  int src, dst;
  if (t < PN*KK) {
    dst = t / KK;
    src = WS_I(OFF_KSRC)[t];
    if (!WS_I(OFF_KKEEP)[t]) return;
  } else {
    int e = t - PN*KK;
    if (e >= *WS_I(OFF_E0C)) return;
    src = WS_I(OFF_E0S)[e];
    dst = WS_I(OFF_E0D)[e];
  }
  float u[32];
  if (src < PN) {
    const float4* up4 = (const float4*)&WS_F(OFF_UPATH)[src*32];
    #pragma unroll
    for (int q = 0; q < 8; q++) {
      float4 w = up4[q];
      u[4*q] = w.x; u[4*q+1] = w.y; u[4*q+2] = w.z; u[4*q+3] = w.w;
    }
  } else {
    int j = src - PN;
    float c0 = WS_F(OFF_CPOS)[2*j], c1 = WS_F(OFF_CPOS)[2*j+1];
    const float* cls = (j < NFREE) ? WS_F(OFF_CFREE) : WS_F(OFF_CCOL);
    const float* mean = WS_F(OFF_MEAN); const float* rstd = WS_F(OFF_RSTD);
    float xn[32];
    #pragma unroll
    for (int f = 0; f < 32; f++) {
      float h = fmaf(c1, ncw1[32+f], fmaf(c0, ncw1[f], cls[f]));
      float tt = (h - mean[f]) * rstd[f];
      tt = fmaf(tt, gamma[f], beta[f]);
      xn[f] = tt > 0.f ? tt : 0.f;
    }
    const float* wcu = WS_F(OFF_WCU); const float* bu = WS_F(OFF_BU);
    for (int f = 0; f < 32; f++) {
      float au = bu[f];
      #pragma unroll
      for (int k = 0; k < 32; k++) au = fmaf(xn[k], wcu[k*32+f], au);
      u[f] = au;
    }
  }
  const float* vd = &WS_F(OFF_VDST)[dst*32];
  float* sb = &WS_F(OFF_SBUF)[dst*32];
  #pragma unroll
  for (int f = 0; f < 32; f++) {
    float r = u[f] + vd[f];
    if (r > 0.f) atomicAdd(&sb[f], r);        // relu; skip zero adds
  }
}

// epilogue per path node: out -> mp1 -> h = x + g -> smooth -> path update + d_out
__global__ __launch_bounds__(256) void k_loopC(char* __restrict__ ws,
    const float* __restrict__ ncw1, const float* __restrict__ gamma,
    const float* __restrict__ beta, const float* __restrict__ ncw2,
    const float* __restrict__ ncb2, const float* __restrict__ m0w2,
    const float* __restrict__ m0b2, const float* __restrict__ m1w1,
    const float* __restrict__ m1b1, const float* __restrict__ m1w2,
    const float* __restrict__ m1b2, const float* __restrict__ snw,
    const float* __restrict__ snb, float* __restrict__ outp) {
  int i = blockIdx.x * 256 + threadIdx.x;
  if (i >= PN) return;
  float s[32];
  #pragma unroll
  for (int f = 0; f < 32; f++) s[f] = WS_F(OFF_SBUF)[i*32+f];
  int deg = WS_I(OFF_DEG0)[i];
  #pragma unroll
  for (int k = 0; k < KK; k++) deg += WS_I(OFF_KKEEP)[i*KK+k];
  float fdeg = (float)deg;

  float o[32];
  for (int f = 0; f < 32; f++) {
    float acc = 0.f;
    #pragma unroll
    for (int k = 0; k < 32; k++) acc = fmaf(s[k], m0w2[k*32+f], acc);
    o[f] = fmaf(fdeg, m0b2[f], acc);
  }
  float t[32];
  for (int f = 0; f < 32; f++) {
    float acc = m1b1[f];
    #pragma unroll
    for (int k = 0; k < 32; k++) acc = fmaf(o[k], m1w1[k*32+f], acc);
    t[f] = acc > 0.f ? acc : 0.f;
  }
  float g[32];
  for (int f = 0; f < 32; f++) {
    float acc = m1b2[f];
    #pragma unroll
    for (int k = 0; k < 32; k++) acc = fmaf(t[k], m1w2[k*32+f], acc);
    g[f] = acc;
  }
  // x_i for this path node
  float p0 = WS_F(OFF_PATH)[2*i], p1 = WS_F(OFF_PATH)[2*i+1];
  const float* cpath = WS_F(OFF_CPATH);
  const float* mean = WS_F(OFF_MEAN); const float* rstd = WS_F(OFF_RSTD);
  float xn[32];
  #pragma unroll
  for (int f = 0; f < 32; f++) {
    float h = fmaf(p1, ncw1[32+f], fmaf(p0, ncw1[f], cpath[f]));
    float tt = (h - mean[f]) * rstd[f];
    tt = fmaf(tt, gamma[f], beta[f]);
    xn[f] = tt > 0.f ? tt : 0.f;
  }
  float sm0 = snb[0], sm1 = snb[1];
  for (int f = 0; f < 32; f++) {
    float acc = ncb2[f];
    #pragma unroll
    for (int k = 0; k < 32; k++) acc = fmaf(xn[k], ncw2[k*32+f], acc);
    float h = acc + g[f];
    sm0 = fmaf(h, snw[2*f],   sm0);
    sm1 = fmaf(h, snw[2*f+1], sm1);
  }
  float np0, np1;
  if (i == 0 || i == PN-1) { np0 = p0; np1 = p1; }  // endpoints fixed
  else                     { np0 = sm0; np1 = sm1; }
  WS_F(OFF_PATH)[2*i]   = np0;
  WS_F(OFF_PATH)[2*i+1] = np1;
  outp[2*i]   = np0;
  outp[2*i+1] = np1;
}

// ---------------- host launch ----------------

extern "C" void kernel_launch(void* const* d_in, const int* in_sizes, int n_in,
                              void* d_out, int out_size, void* d_ws, size_t ws_size,
                              hipStream_t stream) {
  const float* path  = (const float*)d_in[0];
  const float* freep = (const float*)d_in[1];
  const float* collp = (const float*)d_in[2];
  const int*   ei    = (const int*)d_in[4];
  const float* ncw1  = (const float*)d_in[6];
  const float* ncb1  = (const float*)d_in[7];
  const float* gamma = (const float*)d_in[8];
  const float* beta  = (const float*)d_in[9];
  const float* ncw2  = (const float*)d_in[10];
  const float* ncb2  = (const float*)d_in[11];
  const float* m0w1  = (const float*)d_in[12];
  const float* m0b1  = (const float*)d_in[13];
  const float* m0w2  = (const float*)d_in[14];
  const float* m0b2  = (const float*)d_in[15];
  const float* m1w1  = (const float*)d_in[16];
  const float* m1b1  = (const float*)d_in[17];
  const float* m1w2  = (const float*)d_in[18];
  const float* m1b2  = (const float*)d_in[19];
  const float* snw   = (const float*)d_in[20];
  const float* snb   = (const float*)d_in[21];
  char* ws = (char*)d_ws;

  k_init <<<HSIZE/256, 256, 0, stream>>>(ws, path);
  k_cand <<<(NCND+255)/256, 256, 0, stream>>>(ws, freep, collp, ncw1, ncb1);
  k_wprep<<<1, 1024, 0, stream>>>(ws, m0w1, m0b1, ncw1, ncb1, ncw2, ncb2);
  k_edges<<<(NEDGE+255)/256, 256, 0, stream>>>(ws, ei);

  for (int l = 0; l < NLOOP; l++) {
    k_loopA<<<PN+1, 256, 0, stream>>>(ws, ncw1, gamma, beta);
    k_loopB<<<(PN*KK + E0CAP + 255)/256, 256, 0, stream>>>(ws, ncw1, gamma, beta);
    k_loopC<<<2, 256, 0, stream>>>(ws, ncw1, gamma, beta, ncw2, ncb2,
                                   m0w2, m0b2, m1w1, m1b1, m1w2, m1b2,
                                   snw, snb, (float*)d_out);
  }
}